// Round 14
// baseline (248.718 us; speedup 1.0000x reference)
//
#include <hip/hip_runtime.h>
#include <hip/hip_bf16.h>
#include <math.h>

#define B 64
#define O 64
#define F 1024
#define RN 16
#define RD 256
#define DEPTH 2
#define M (B*O)

typedef __attribute__((ext_vector_type(8))) _Float16 half8;
typedef __attribute__((ext_vector_type(4))) float f32x4;

#define RES_SCALE 2048.0f          // 2^11
#define RES_INV  (1.0f/2048.0f)

// ---------- fp16 split helpers: x = h + l*2^-11 (l stored pre-scaled) ----------
__device__ __forceinline__ unsigned short h2u(_Float16 h) {
  union { _Float16 h; unsigned short u; } c; c.h = h; return c.u;
}
__device__ __forceinline__ void split2(float x, unsigned short& h, unsigned short& l) {
  _Float16 hh = (_Float16)x;                       // RNE
  _Float16 ll = (_Float16)((x - (float)hh) * RES_SCALE);
  h = h2u(hh); l = h2u(ll);
}

__device__ __forceinline__ void gload_lds16(const unsigned short* g, void* l) {
  __builtin_amdgcn_global_load_lds(
      (const __attribute__((address_space(1))) unsigned int*)g,
      (__attribute__((address_space(3))) unsigned int*)l, 16, 0, 0);
}

// ---------------- A reductions: A1[b,o,o2] = sum_r A, A2[b,o,r] = sum_o2 A ----
__global__ __launch_bounds__(256) void k_reduceA(const float* __restrict__ A,
                                                 float* __restrict__ A1,
                                                 float* __restrict__ A2) {
  __shared__ float row[O * RN];
  const int bo = blockIdx.x;
  const int t = threadIdx.x;
  *reinterpret_cast<float4*>(&row[t * 4]) =
      *reinterpret_cast<const float4*>(&A[(size_t)bo * (O * RN) + t * 4]);
  __syncthreads();
  if (t < O) {
    float s = 0.f;
#pragma unroll
    for (int r = 0; r < RN; ++r) s += row[t * RN + r];
    A1[(size_t)bo * O + t] = s;
  } else if (t < O + RN) {
    const int r = t - O;
    float s = 0.f;
#pragma unroll
    for (int o2 = 0; o2 < O; ++o2) s += row[o2 * RN + r];
    A2[(size_t)bo * RN + r] = s;
  }
}

// ------- xr_r = R @ Wrel[i][F:] + brel[i] -> xrr[layer][RN][F], both layers ---
__global__ __launch_bounds__(256) void k_xrr(const float* __restrict__ R,
                                             const float* __restrict__ Wrel,
                                             const float* __restrict__ brel,
                                             float* __restrict__ xrr) {
  const int layer = blockIdx.y;
  const float* Wr = Wrel + (size_t)layer * (F + RD) * F + (size_t)F * F;
  const float* br = brel + (size_t)layer * F;
  const int r = blockIdx.x >> 2;
  const int n = ((blockIdx.x & 3) << 8) + threadIdx.x;
  float s = br[n];
  for (int k = 0; k < RD; ++k) s += R[r * RD + k] * Wr[(size_t)k * F + n];
  xrr[(size_t)layer * RN * F + (size_t)r * F + n] = s;
}

// ---------------- split X [4096][1024] f32 -> Xh, Xl fp16 (row-major) --------
__global__ __launch_bounds__(256) void k_splitX(const float* __restrict__ X,
                                                unsigned short* __restrict__ Xh,
                                                unsigned short* __restrict__ Xl) {
  const size_t i = ((size_t)blockIdx.x * 256 + threadIdx.x) * 4;
  const float4 v = *reinterpret_cast<const float4*>(&X[i]);
  unsigned short h0, h1, h2, h3, l0, l1, l2, l3;
  split2(v.x, h0, l0); split2(v.y, h1, l1); split2(v.z, h2, l2); split2(v.w, h3, l3);
  uint2 hp, lp;
  hp.x = (unsigned)h0 | ((unsigned)h1 << 16); hp.y = (unsigned)h2 | ((unsigned)h3 << 16);
  lp.x = (unsigned)l0 | ((unsigned)l1 << 16); lp.y = (unsigned)l2 | ((unsigned)l3 << 16);
  *reinterpret_cast<uint2*>(&Xh[i]) = hp;
  *reinterpret_cast<uint2*>(&Xl[i]) = lp;
}

// -- split + transpose W for BOTH layers upfront.
// z = layer*2 + sel; sel 0: Wself -> rows [0,1024); sel 1: Wrel[:F] -> rows [1024,2048).
__global__ __launch_bounds__(256) void k_splitW2(const float* __restrict__ Wself,
                                                 const float* __restrict__ Wrel,
                                                 unsigned short* __restrict__ Wht,
                                                 unsigned short* __restrict__ Wlt) {
  __shared__ float T[32][33];
  const int layer = blockIdx.z >> 1;
  const int sel = blockIdx.z & 1;
  const float* W = sel ? (Wrel + (size_t)layer * (F + RD) * F)
                       : (Wself + (size_t)layer * F * F);
  const size_t obase = (size_t)layer * 2048 * 1024 + (size_t)(sel ? 1024 : 0) * 1024;
  const int k0 = blockIdx.x * 32, n0 = blockIdx.y * 32;
  const int t = threadIdx.x;
  const int r = t >> 3, c4 = (t & 7) << 2;
  const float4 v = *reinterpret_cast<const float4*>(&W[(size_t)(k0 + r) * 1024 + n0 + c4]);
  T[r][c4] = v.x; T[r][c4 + 1] = v.y; T[r][c4 + 2] = v.z; T[r][c4 + 3] = v.w;
  __syncthreads();
  unsigned short h[4], l[4];
#pragma unroll
  for (int j = 0; j < 4; ++j) split2(T[c4 + j][r], h[j], l[j]);
  uint2 hp, lp;
  hp.x = (unsigned)h[0] | ((unsigned)h[1] << 16); hp.y = (unsigned)h[2] | ((unsigned)h[3] << 16);
  lp.x = (unsigned)l[0] | ((unsigned)l[1] << 16); lp.y = (unsigned)l[2] | ((unsigned)l[3] << 16);
  const size_t o = obase + (size_t)(n0 + r) * 1024 + k0 + c4;
  *reinterpret_cast<uint2*>(&Wht[o]) = hp;
  *reinterpret_cast<uint2*>(&Wlt[o]) = lp;
}

// ---------------- staging + compute helpers (8-wave block, BK=128) -----------
// LDS tile: [128 rows][256 B] per matrix (32 KB); XOR swizzle within 128B half:
// content(row, b) = global k-byte (b ^ ((row&7)<<4)).
// 64 chunks of 1KB (= 4 rows); wave w stages chunks w*8..w*8+7 (w<4: A, else B).
__device__ __forceinline__ void stage_tiles8(const unsigned short* __restrict__ Asrc,
                                             const unsigned short* __restrict__ Bsrc,
                                             int bm, int bn, int k0,
                                             int w, int lane,
                                             char* Al, char* Bl) {
  const int rsub = lane >> 4;                 // row within chunk
  const int dinrow = (lane & 15) << 4;        // dest byte within 256B row
#pragma unroll
  for (int i = 0; i < 8; ++i) {
    const int c = (w << 3) + i;               // 0..63, wave-uniform
    const int cc = c & 31;
    const int row = (cc << 2) + rsub;
    const int sbyte = dinrow ^ ((row & 7) << 4);   // pre-swizzled SOURCE byte
    const unsigned short* src = (c < 32) ? Asrc : Bsrc;
    const int rbase = (c < 32) ? bm : bn;
    char* ldst = (c < 32) ? Al : Bl;
    gload_lds16(src + ((size_t)(rbase + row) << 10) + k0 + (sbyte >> 1), ldst + (cc << 10));
  }
}

// per-wave 64x32 output: 4 m-frags x 2 n-frags, K=128 per step (4 kk slices)
__device__ __forceinline__ void compute_tile8(const char* Al, const char* Bl,
                                              int ar, int br, int lslot,
                                              f32x4 (&acc)[4][2]) {
#pragma unroll
  for (int kk = 0; kk < 4; ++kk) {
    const int kb = (kk << 6) + lslot;
    half8 a[4], b[2];
#pragma unroll
    for (int m = 0; m < 4; ++m) {
      const int row = ar + m * 16;
      a[m] = *reinterpret_cast<const half8*>(&Al[(row << 8) + (kb ^ ((row & 7) << 4))]);
    }
#pragma unroll
    for (int n = 0; n < 2; ++n) {
      const int row = br + n * 16;
      b[n] = *reinterpret_cast<const half8*>(&Bl[(row << 8) + (kb ^ ((row & 7) << 4))]);
    }
#pragma unroll
    for (int m = 0; m < 4; ++m)
#pragma unroll
      for (int n = 0; n < 2; ++n)
        acc[m][n] = __builtin_amdgcn_mfma_f32_16x16x32_f16(a[m], b[n], acc[m][n], 0, 0, 0);
  }
}

// 8-step inner loop (K=1024), fixed sources, single accumulator, 2-barrier.
__device__ __forceinline__ void gemm_piece8(const unsigned short* __restrict__ Asrc,
                                            const unsigned short* __restrict__ Bsrc,
                                            int bm, int bn, int w, int lane,
                                            int ar, int br, int lslot,
                                            char* Al, char* Bl, f32x4 (&acc)[4][2]) {
  for (int st = 0; st < 8; ++st) {
    stage_tiles8(Asrc, Bsrc, bm, bn, st << 7, w, lane, Al, Bl);
    __syncthreads();
    compute_tile8(Al, Bl, ar, br, lslot, acc);
    __syncthreads();
  }
}

// ------- fused MFMA GEMM (8 waves / 512 threads, BK=128) ----------------------
// xrx half (bn>=1024): C = Xh@Wh + 2^-11*(Xh@Wl_st + Xl_st@Wh), K=3072 always.
// xs  half (bn< 1024): same if xs_full, else single product Xh@Wh (K=1024).
__global__ __launch_bounds__(512) void k_gemm_mfma(
    const unsigned short* __restrict__ Xh, const unsigned short* __restrict__ Xl,
    const unsigned short* __restrict__ Wht, const unsigned short* __restrict__ Wlt,
    float* __restrict__ xs, float* __restrict__ xrx, int xs_full) {
  __shared__ __align__(16) char Al[128 * 256];  // 32 KB
  __shared__ __align__(16) char Bl[128 * 256];  // 32 KB
  const int t = threadIdx.x;
  const int lane = t & 63, w = t >> 6;          // w 0..7
  // bid pairs (2k,2k+1) share the A-panel and mix long(xrx)/short(xs) blocks.
  const int bid = blockIdx.x;
  const int half = bid & 1;                 // 0 -> xrx (long), 1 -> xs
  int e = bid >> 1;                          // 0..255
  e = (e & 7) * 32 + (e >> 3);               // XCD swizzle, bijective on 256
  const int bm = (e & 31) * 128;
  const int bn = (e >> 5) * 128 + (half ? 0 : 1024);
  const int wr = w >> 2, wc = w & 3;         // wave tile: rows wr*64, cols wc*32
  const bool full = (half == 0) || xs_full;

  f32x4 accM[4][2], accR[4][2];
#pragma unroll
  for (int m = 0; m < 4; ++m)
#pragma unroll
    for (int n = 0; n < 2; ++n) { accM[m][n] = (f32x4)0.f; accR[m][n] = (f32x4)0.f; }

  const int ar = wr * 64 + (lane & 15);
  const int br = wc * 32 + (lane & 15);
  const int lslot = (lane >> 4) << 4;

  // piece 0: Xh@Wh -> accM (K=1024)
  gemm_piece8(Xh, Wht, bm, bn, w, lane, ar, br, lslot, Al, Bl, accM);
  // pieces 1,2: Xh@Wl_st, Xl_st@Wh -> accR (K=2048)
  if (full) {
    gemm_piece8(Xh, Wlt, bm, bn, w, lane, ar, br, lslot, Al, Bl, accR);
    gemm_piece8(Xl, Wht, bm, bn, w, lane, ar, br, lslot, Al, Bl, accR);
  }

  // epilogue: cols [0,1024) -> xs, [1024,2048) -> xrx (both [4096][1024])
  float* dst = (bn < 1024) ? xs : xrx;
  const int coff = bn & 1023;
  const int lrow = (lane >> 4) << 2;
  const int lcol = lane & 15;
#pragma unroll
  for (int m = 0; m < 4; ++m)
#pragma unroll
    for (int n = 0; n < 2; ++n) {
      const int gr = bm + wr * 64 + m * 16 + lrow;
      const int gc = coff + wc * 32 + n * 16 + lcol;
#pragma unroll
      for (int i = 0; i < 4; ++i)
        dst[((size_t)(gr + i) << 10) + gc] = accM[m][n][i] + accR[m][n][i] * RES_INV;
    }
}

// ------- out = tanh(xs + bself + A1[b]@xr_x[b] + A2[b]@xr_r + x_in) ----------
// Optionally also emits the fp16 split of out (for the next layer's GEMM).
__global__ __launch_bounds__(256) void k_agg(const float* __restrict__ A1,
                                             const float* __restrict__ A2,
                                             const float* __restrict__ xrx,
                                             const float* __restrict__ xrr,
                                             const float* __restrict__ xs,
                                             const float* __restrict__ bias,
                                             const float* __restrict__ xin,
                                             float* __restrict__ xout,
                                             unsigned short* __restrict__ XhO,
                                             unsigned short* __restrict__ XlO) {
  __shared__ float A1s[O][O + 1];
  __shared__ float A2s[O][RN + 1];
  __shared__ float Xls[O][132];
  __shared__ float Rls[RN][132];
  const int b = blockIdx.x;
  const int f0 = blockIdx.y * 128;
  const int t = threadIdx.x;

#pragma unroll
  for (int i = 0; i < 4; ++i) {
    const int gi = i * 1024 + t * 4;
    const float4 v = *reinterpret_cast<const float4*>(&A1[(size_t)b * O * O + gi]);
    const int o = gi >> 6, c = gi & 63;
    A1s[o][c] = v.x; A1s[o][c + 1] = v.y; A1s[o][c + 2] = v.z; A1s[o][c + 3] = v.w;
  }
  {
    const int gi = t * 4;
    const float4 v = *reinterpret_cast<const float4*>(&A2[(size_t)b * O * RN + gi]);
    const int o = gi >> 4, c = gi & 15;
    A2s[o][c] = v.x; A2s[o][c + 1] = v.y; A2s[o][c + 2] = v.z; A2s[o][c + 3] = v.w;
  }
#pragma unroll
  for (int i = 0; i < 8; ++i) {
    const int gi = i * 1024 + t * 4;
    const int o2 = gi >> 7, c = gi & 127;
    const float4 v = *reinterpret_cast<const float4*>(&xrx[((size_t)(b * O + o2)) * F + f0 + c]);
    Xls[o2][c] = v.x; Xls[o2][c + 1] = v.y; Xls[o2][c + 2] = v.z; Xls[o2][c + 3] = v.w;
  }
#pragma unroll
  for (int i = 0; i < 2; ++i) {
    const int gi = i * 1024 + t * 4;
    const int r = gi >> 7, c = gi & 127;
    const float4 v = *reinterpret_cast<const float4*>(&xrr[(size_t)r * F + f0 + c]);
    Rls[r][c] = v.x; Rls[r][c + 1] = v.y; Rls[r][c + 2] = v.z; Rls[r][c + 3] = v.w;
  }
  __syncthreads();

  const int ob = (t >> 4) << 2;
  const int fc = (t & 15) << 2;
  float acc[4][8];
#pragma unroll
  for (int i = 0; i < 4; ++i)
#pragma unroll
    for (int j = 0; j < 8; ++j) acc[i][j] = 0.f;

#pragma unroll 4
  for (int o2 = 0; o2 < O; ++o2) {
    const float4 xa = *reinterpret_cast<const float4*>(&Xls[o2][fc]);
    const float4 xb = *reinterpret_cast<const float4*>(&Xls[o2][fc + 64]);
#pragma unroll
    for (int io = 0; io < 4; ++io) {
      const float a = A1s[ob + io][o2];
      acc[io][0] += a * xa.x; acc[io][1] += a * xa.y; acc[io][2] += a * xa.z; acc[io][3] += a * xa.w;
      acc[io][4] += a * xb.x; acc[io][5] += a * xb.y; acc[io][6] += a * xb.z; acc[io][7] += a * xb.w;
    }
  }
#pragma unroll
  for (int r = 0; r < RN; ++r) {
    const float4 xa = *reinterpret_cast<const float4*>(&Rls[r][fc]);
    const float4 xb = *reinterpret_cast<const float4*>(&Rls[r][fc + 64]);
#pragma unroll
    for (int io = 0; io < 4; ++io) {
      const float a = A2s[ob + io][r];
      acc[io][0] += a * xa.x; acc[io][1] += a * xa.y; acc[io][2] += a * xa.z; acc[io][3] += a * xa.w;
      acc[io][4] += a * xb.x; acc[io][5] += a * xb.y; acc[io][6] += a * xb.z; acc[io][7] += a * xb.w;
    }
  }

#pragma unroll
  for (int io = 0; io < 4; ++io) {
    const size_t base = ((size_t)(b * O + ob + io)) * F + f0;
#pragma unroll
    for (int seg = 0; seg < 2; ++seg) {
      const size_t idx = base + seg * 64 + fc;
      const float4 s = *reinterpret_cast<const float4*>(&xs[idx]);
      const float4 bv = *reinterpret_cast<const float4*>(&bias[f0 + seg * 64 + fc]);
      const float4 xi = *reinterpret_cast<const float4*>(&xin[idx]);
      float4 o;
      o.x = tanhf(acc[io][seg * 4 + 0] + s.x + bv.x + xi.x);
      o.y = tanhf(acc[io][seg * 4 + 1] + s.y + bv.y + xi.y);
      o.z = tanhf(acc[io][seg * 4 + 2] + s.z + bv.z + xi.z);
      o.w = tanhf(acc[io][seg * 4 + 3] + s.w + bv.w + xi.w);
      *reinterpret_cast<float4*>(&xout[idx]) = o;
      if (XhO) {
        unsigned short h0, h1, h2, h3, l0, l1, l2, l3;
        split2(o.x, h0, l0); split2(o.y, h1, l1); split2(o.z, h2, l2); split2(o.w, h3, l3);
        uint2 hp, lp;
        hp.x = (unsigned)h0 | ((unsigned)h1 << 16); hp.y = (unsigned)h2 | ((unsigned)h3 << 16);
        lp.x = (unsigned)l0 | ((unsigned)l1 << 16); lp.y = (unsigned)l2 | ((unsigned)l3 << 16);
        *reinterpret_cast<uint2*>(&XhO[idx]) = hp;
        *reinterpret_cast<uint2*>(&XlO[idx]) = lp;
      }
    }
  }
}

extern "C" void kernel_launch(void* const* d_in, const int* in_sizes, int n_in,
                              void* d_out, int out_size, void* d_ws, size_t ws_size,
                              hipStream_t stream) {
  const float* x0    = (const float*)d_in[0];
  const float* A     = (const float*)d_in[1];
  const float* R     = (const float*)d_in[2];
  const float* Wself = (const float*)d_in[3];
  const float* bself = (const float*)d_in[4];
  const float* Wrel  = (const float*)d_in[5];
  const float* brel  = (const float*)d_in[6];
  float* out = (float*)d_out;

  float* ws  = (float*)d_ws;
  float* A1  = ws;                               // 1 MB
  float* A2  = A1 + (size_t)M * O;               // 0.25 MB
  float* xrr = A2 + (size_t)M * RN;              // 2 layers x RN x F
  float* xs  = xrr + (size_t)2 * RN * F;         // 16 MB
  float* xrx = xs + (size_t)M * F;               // 16 MB
  unsigned short* Xh  = (unsigned short*)(xrx + (size_t)M * F);    // 8 MB
  unsigned short* Xl  = Xh + (size_t)M * F;                        // 8 MB
  unsigned short* Wht = Xl + (size_t)M * F;      // 2 layers x [2048][1024] = 8 MB
  unsigned short* Wlt = Wht + (size_t)2 * 2048 * 1024;             // 8 MB
  // total ws use ~65 MB

  k_reduceA<<<M, 256, 0, stream>>>(A, A1, A2);
  k_splitX<<<4096, 256, 0, stream>>>(x0, Xh, Xl);
  k_splitW2<<<dim3(32, 32, 4), 256, 0, stream>>>(Wself, Wrel, Wht, Wlt);
  k_xrr<<<dim3(RN * 4, 2), 256, 0, stream>>>(R, Wrel, brel, xrr);

  for (int i = 0; i < DEPTH; ++i) {
    const float* X = (i == 0) ? x0 : out;
    const unsigned short* Wht_i = Wht + (size_t)i * 2048 * 1024;
    const unsigned short* Wlt_i = Wlt + (size_t)i * 2048 * 1024;
    const int xs_full = (i + 1 < DEPTH) ? 1 : 0;
    k_gemm_mfma<<<512, 512, 0, stream>>>(Xh, Xl, Wht_i, Wlt_i, xs, xrx, xs_full);
    const bool emit = (i + 1 < DEPTH);
    k_agg<<<dim3(B, F / 128), 256, 0, stream>>>(A1, A2, xrx,
                                                xrr + (size_t)i * RN * F, xs,
                                                bself + (size_t)i * F, X, out,
                                                emit ? Xh : nullptr,
                                                emit ? Xl : nullptr);
  }
}

// Round 15
// 169.891 us; speedup vs baseline: 1.4640x; 1.4640x over previous
//
#include <hip/hip_runtime.h>
#include <hip/hip_bf16.h>
#include <math.h>

#define B 64
#define O 64
#define F 1024
#define RN 16
#define RD 256
#define DEPTH 2
#define M (B*O)

typedef __attribute__((ext_vector_type(8))) _Float16 half8;
typedef __attribute__((ext_vector_type(4))) float f32x4;

#define RES_SCALE 2048.0f          // 2^11
#define RES_INV  (1.0f/2048.0f)

// ---------- fp16 split helpers: x = h + l*2^-11 (l stored pre-scaled) ----------
__device__ __forceinline__ unsigned short h2u(_Float16 h) {
  union { _Float16 h; unsigned short u; } c; c.h = h; return c.u;
}
__device__ __forceinline__ void split2(float x, unsigned short& h, unsigned short& l) {
  _Float16 hh = (_Float16)x;                       // RNE
  _Float16 ll = (_Float16)((x - (float)hh) * RES_SCALE);
  h = h2u(hh); l = h2u(ll);
}

__device__ __forceinline__ void gload_lds16(const unsigned short* g, void* l) {
  __builtin_amdgcn_global_load_lds(
      (const __attribute__((address_space(1))) unsigned int*)g,
      (__attribute__((address_space(3))) unsigned int*)l, 16, 0, 0);
}

// ------- merged prep 1: bid<4096 -> A reductions; else -> splitX --------------
__global__ __launch_bounds__(256) void k_prep(const float* __restrict__ A,
                                              const float* __restrict__ X,
                                              float* __restrict__ A1,
                                              float* __restrict__ A2,
                                              unsigned short* __restrict__ Xh,
                                              unsigned short* __restrict__ Xl) {
  __shared__ float row[O * RN];
  const int t = threadIdx.x;
  if (blockIdx.x < 4096) {
    const int bo = blockIdx.x;
    *reinterpret_cast<float4*>(&row[t * 4]) =
        *reinterpret_cast<const float4*>(&A[(size_t)bo * (O * RN) + t * 4]);
    __syncthreads();
    if (t < O) {
      float s = 0.f;
#pragma unroll
      for (int r = 0; r < RN; ++r) s += row[t * RN + r];
      A1[(size_t)bo * O + t] = s;
    } else if (t < O + RN) {
      const int r = t - O;
      float s = 0.f;
#pragma unroll
      for (int o2 = 0; o2 < O; ++o2) s += row[o2 * RN + r];
      A2[(size_t)bo * RN + r] = s;
    }
  } else {
    const size_t i = ((size_t)(blockIdx.x - 4096) * 256 + t) * 4;
    const float4 v = *reinterpret_cast<const float4*>(&X[i]);
    unsigned short h0, h1, h2, h3, l0, l1, l2, l3;
    split2(v.x, h0, l0); split2(v.y, h1, l1); split2(v.z, h2, l2); split2(v.w, h3, l3);
    uint2 hp, lp;
    hp.x = (unsigned)h0 | ((unsigned)h1 << 16); hp.y = (unsigned)h2 | ((unsigned)h3 << 16);
    lp.x = (unsigned)l0 | ((unsigned)l1 << 16); lp.y = (unsigned)l2 | ((unsigned)l3 << 16);
    *reinterpret_cast<uint2*>(&Xh[i]) = hp;
    *reinterpret_cast<uint2*>(&Xl[i]) = lp;
  }
}

// ------- merged prep 2: bid<4096 -> splitW both layers; else -> xrr -----------
__global__ __launch_bounds__(256) void k_prepW(const float* __restrict__ Wself,
                                               const float* __restrict__ Wrel,
                                               const float* __restrict__ brel,
                                               const float* __restrict__ R,
                                               unsigned short* __restrict__ Wht,
                                               unsigned short* __restrict__ Wlt,
                                               float* __restrict__ xrr) {
  __shared__ float T[32][33];
  const int t = threadIdx.x;
  const int bid = blockIdx.x;
  if (bid < 4096) {
    const int z = bid >> 10;                 // layer*2 + sel
    const int rem = bid & 1023;
    const int k0 = (rem & 31) * 32, n0 = (rem >> 5) * 32;
    const int layer = z >> 1;
    const int sel = z & 1;
    const float* W = sel ? (Wrel + (size_t)layer * (F + RD) * F)
                         : (Wself + (size_t)layer * F * F);
    const size_t obase = (size_t)layer * 2048 * 1024 + (size_t)(sel ? 1024 : 0) * 1024;
    const int r = t >> 3, c4 = (t & 7) << 2;
    const float4 v = *reinterpret_cast<const float4*>(&W[(size_t)(k0 + r) * 1024 + n0 + c4]);
    T[r][c4] = v.x; T[r][c4 + 1] = v.y; T[r][c4 + 2] = v.z; T[r][c4 + 3] = v.w;
    __syncthreads();
    unsigned short h[4], l[4];
#pragma unroll
    for (int j = 0; j < 4; ++j) split2(T[c4 + j][r], h[j], l[j]);
    uint2 hp, lp;
    hp.x = (unsigned)h[0] | ((unsigned)h[1] << 16); hp.y = (unsigned)h[2] | ((unsigned)h[3] << 16);
    lp.x = (unsigned)l[0] | ((unsigned)l[1] << 16); lp.y = (unsigned)l[2] | ((unsigned)l[3] << 16);
    const size_t o = obase + (size_t)(n0 + r) * 1024 + k0 + c4;
    *reinterpret_cast<uint2*>(&Wht[o]) = hp;
    *reinterpret_cast<uint2*>(&Wlt[o]) = lp;
  } else {
    const int r4 = bid - 4096;               // 0..127
    const int layer = r4 >> 6;
    const int idx = r4 & 63;
    const float* Wr = Wrel + (size_t)layer * (F + RD) * F + (size_t)F * F;
    const float* br = brel + (size_t)layer * F;
    const int r = idx >> 2;
    const int n = ((idx & 3) << 8) + t;
    float s = br[n];
    for (int k = 0; k < RD; ++k) s += R[r * RD + k] * Wr[(size_t)k * F + n];
    xrr[(size_t)layer * RN * F + (size_t)r * F + n] = s;
  }
}

// ---------------- staging + compute helpers (8-wave block, BK=64) ------------
// R11-proven: 32 chunks of 1KB (8 rows x 128B); wave w stages 4 chunks.
__device__ __forceinline__ void stage_tiles8(const unsigned short* __restrict__ Asrc,
                                             const unsigned short* __restrict__ Bsrc,
                                             int bm, int bn, int k0,
                                             int w, int lane,
                                             char* Al, char* Bl) {
  const int srow = lane >> 3;
  const int sin = (lane & 7) << 4;
#pragma unroll
  for (int i = 0; i < 4; ++i) {
    const int c = (w << 2) + i;          // 0..31, wave-uniform
    const int cc = c & 15;
    const int row = (cc << 3) + srow;
    const int inrow = sin ^ ((row & 7) << 4);   // pre-swizzled SOURCE byte
    const unsigned short* src = (c < 16) ? Asrc : Bsrc;
    const int rbase = (c < 16) ? bm : bn;
    char* ldst = (c < 16) ? Al : Bl;
    gload_lds16(src + ((size_t)(rbase + row) << 10) + k0 + (inrow >> 1), ldst + (cc << 10));
  }
}

// per-wave 64x32 output: 4 m-frags x 2 n-frags
__device__ __forceinline__ void compute_tile8(const char* Al, const char* Bl,
                                              int ar, int br, int kbyte,
                                              f32x4 (&acc)[4][2]) {
#pragma unroll
  for (int kk = 0; kk < 2; ++kk) {
    half8 a[4], b[2];
#pragma unroll
    for (int m = 0; m < 4; ++m) {
      const int row = ar + m * 16;
      const int off = (row << 7) + (((kk << 6) + kbyte) ^ ((row & 7) << 4));
      a[m] = *reinterpret_cast<const half8*>(&Al[off]);
    }
#pragma unroll
    for (int n = 0; n < 2; ++n) {
      const int row = br + n * 16;
      const int off = (row << 7) + (((kk << 6) + kbyte) ^ ((row & 7) << 4));
      b[n] = *reinterpret_cast<const half8*>(&Bl[off]);
    }
#pragma unroll
    for (int m = 0; m < 4; ++m)
#pragma unroll
      for (int n = 0; n < 2; ++n)
        acc[m][n] = __builtin_amdgcn_mfma_f32_16x16x32_f16(a[m], b[n], acc[m][n], 0, 0, 0);
  }
}

// 16-kt inner loop (K=1024), fixed sources, single accumulator, 2-barrier.
__device__ __forceinline__ void gemm_piece8(const unsigned short* __restrict__ Asrc,
                                            const unsigned short* __restrict__ Bsrc,
                                            int bm, int bn, int w, int lane,
                                            int ar, int br, int kbyte,
                                            char* Al, char* Bl, f32x4 (&acc)[4][2]) {
  for (int kt = 0; kt < 16; ++kt) {
    stage_tiles8(Asrc, Bsrc, bm, bn, kt << 6, w, lane, Al, Bl);
    __syncthreads();
    compute_tile8(Al, Bl, ar, br, kbyte, acc);
    __syncthreads();
  }
}

// ------- layer-1 fused MFMA GEMM (R11 exact) ----------------------------------
// xrx half (bn>=1024): C = Xh@Wh + 2^-11*(Xh@Wl_st + Xl_st@Wh), K=3072.
// xs  half (bn< 1024): same (xs_full=1 for layer 1).
__global__ __launch_bounds__(512) void k_gemm_mfma(
    const unsigned short* __restrict__ Xh, const unsigned short* __restrict__ Xl,
    const unsigned short* __restrict__ Wht, const unsigned short* __restrict__ Wlt,
    float* __restrict__ xs, float* __restrict__ xrx, int xs_full) {
  __shared__ __align__(16) char Al[128 * 128];
  __shared__ __align__(16) char Bl[128 * 128];
  const int t = threadIdx.x;
  const int lane = t & 63, w = t >> 6;
  const int bid = blockIdx.x;
  const int half = bid & 1;                 // 0 -> xrx (long), 1 -> xs
  int e = bid >> 1;
  e = (e & 7) * 32 + (e >> 3);               // XCD swizzle, bijective on 256
  const int bm = (e & 31) * 128;
  const int bn = (e >> 5) * 128 + (half ? 0 : 1024);
  const int wr = w >> 2, wc = w & 3;
  const bool full = (half == 0) || xs_full;

  f32x4 accM[4][2], accR[4][2];
#pragma unroll
  for (int m = 0; m < 4; ++m)
#pragma unroll
    for (int n = 0; n < 2; ++n) { accM[m][n] = (f32x4)0.f; accR[m][n] = (f32x4)0.f; }

  const int ar = wr * 64 + (lane & 15);
  const int br = wc * 32 + (lane & 15);
  const int kbyte = (lane >> 4) << 4;

  gemm_piece8(Xh, Wht, bm, bn, w, lane, ar, br, kbyte, Al, Bl, accM);
  if (full) {
    gemm_piece8(Xh, Wlt, bm, bn, w, lane, ar, br, kbyte, Al, Bl, accR);
    gemm_piece8(Xl, Wht, bm, bn, w, lane, ar, br, kbyte, Al, Bl, accR);
  }

  float* dst = (bn < 1024) ? xs : xrx;
  const int coff = bn & 1023;
  const int lrow = (lane >> 4) << 2;
  const int lcol = lane & 15;
#pragma unroll
  for (int m = 0; m < 4; ++m)
#pragma unroll
    for (int n = 0; n < 2; ++n) {
      const int gr = bm + wr * 64 + m * 16 + lrow;
      const int gc = coff + wc * 32 + n * 16 + lcol;
#pragma unroll
      for (int i = 0; i < 4; ++i)
        dst[((size_t)(gr + i) << 10) + gc] = accM[m][n][i] + accR[m][n][i] * RES_INV;
    }
}

// ------- layer-2 GEMM: uniform 16-step blocks, 4 roles per tile-index ---------
// role 0: xs  = Xh@Wh (cols 0..1023)       role 1: xrx = Xh@Wh (cols 1024..)
// role 2: P1  = Xh@Wl_st (raw)             role 3: P2  = Xl_st@Wh (raw)
// consumer: xrx_eff = xrx + (P1+P2)*2^-11; xs needs no residual (last layer).
__global__ __launch_bounds__(512) void k_gemm_l2(
    const unsigned short* __restrict__ Xh, const unsigned short* __restrict__ Xl,
    const unsigned short* __restrict__ Wht, const unsigned short* __restrict__ Wlt,
    float* __restrict__ xs, float* __restrict__ xrx,
    float* __restrict__ P1, float* __restrict__ P2) {
  __shared__ __align__(16) char Al[128 * 128];
  __shared__ __align__(16) char Bl[128 * 128];
  const int t = threadIdx.x;
  const int lane = t & 63, w = t >> 6;
  const int bid = blockIdx.x;
  const int role = bid & 3;
  int e = bid >> 2;
  e = (e & 7) * 32 + (e >> 3);               // XCD swizzle, bijective on 256
  const int bm = (e & 31) * 128;
  const int colblk = (e >> 5) * 128;
  const int bn = (role == 0) ? colblk : 1024 + colblk;
  const unsigned short* Asrc = (role == 3) ? Xl : Xh;
  const unsigned short* Bsrc = (role == 2) ? Wlt : Wht;
  float* dst = (role == 0) ? xs : (role == 1) ? xrx : (role == 2) ? P1 : P2;
  const int wr = w >> 2, wc = w & 3;

  f32x4 acc[4][2];
#pragma unroll
  for (int m = 0; m < 4; ++m)
#pragma unroll
    for (int n = 0; n < 2; ++n) acc[m][n] = (f32x4)0.f;

  const int ar = wr * 64 + (lane & 15);
  const int br = wc * 32 + (lane & 15);
  const int kbyte = (lane >> 4) << 4;

  gemm_piece8(Asrc, Bsrc, bm, bn, w, lane, ar, br, kbyte, Al, Bl, acc);

  const int lrow = (lane >> 4) << 2;
  const int lcol = lane & 15;
#pragma unroll
  for (int m = 0; m < 4; ++m)
#pragma unroll
    for (int n = 0; n < 2; ++n) {
      const int gr = bm + wr * 64 + m * 16 + lrow;
      const int gc = colblk + wc * 32 + n * 16 + lcol;
#pragma unroll
      for (int i = 0; i < 4; ++i)
        dst[((size_t)(gr + i) << 10) + gc] = acc[m][n][i];
    }
}

// ------- out = tanh(xs + bself + A1[b]@xr_x[b] + A2[b]@xr_r + x_in) ----------
// use_p: xr_x = xrx + (P1+P2)*2^-11 (layer 2); else xr_x = xrx (layer 1).
__global__ __launch_bounds__(256) void k_agg(const float* __restrict__ A1,
                                             const float* __restrict__ A2,
                                             const float* __restrict__ xrx,
                                             const float* __restrict__ P1,
                                             const float* __restrict__ P2,
                                             const float* __restrict__ xrr,
                                             const float* __restrict__ xs,
                                             const float* __restrict__ bias,
                                             const float* __restrict__ xin,
                                             float* __restrict__ xout,
                                             unsigned short* __restrict__ XhO,
                                             unsigned short* __restrict__ XlO,
                                             int use_p) {
  __shared__ float A1s[O][O + 1];
  __shared__ float A2s[O][RN + 1];
  __shared__ float Xls[O][132];
  __shared__ float Rls[RN][132];
  const int b = blockIdx.x;
  const int f0 = blockIdx.y * 128;
  const int t = threadIdx.x;

#pragma unroll
  for (int i = 0; i < 4; ++i) {
    const int gi = i * 1024 + t * 4;
    const float4 v = *reinterpret_cast<const float4*>(&A1[(size_t)b * O * O + gi]);
    const int o = gi >> 6, c = gi & 63;
    A1s[o][c] = v.x; A1s[o][c + 1] = v.y; A1s[o][c + 2] = v.z; A1s[o][c + 3] = v.w;
  }
  {
    const int gi = t * 4;
    const float4 v = *reinterpret_cast<const float4*>(&A2[(size_t)b * O * RN + gi]);
    const int o = gi >> 4, c = gi & 15;
    A2s[o][c] = v.x; A2s[o][c + 1] = v.y; A2s[o][c + 2] = v.z; A2s[o][c + 3] = v.w;
  }
#pragma unroll
  for (int i = 0; i < 8; ++i) {
    const int gi = i * 1024 + t * 4;
    const int o2 = gi >> 7, c = gi & 127;
    const size_t pidx = ((size_t)(b * O + o2)) * F + f0 + c;
    float4 v = *reinterpret_cast<const float4*>(&xrx[pidx]);
    if (use_p) {
      const float4 p1 = *reinterpret_cast<const float4*>(&P1[pidx]);
      const float4 p2 = *reinterpret_cast<const float4*>(&P2[pidx]);
      v.x += (p1.x + p2.x) * RES_INV; v.y += (p1.y + p2.y) * RES_INV;
      v.z += (p1.z + p2.z) * RES_INV; v.w += (p1.w + p2.w) * RES_INV;
    }
    Xls[o2][c] = v.x; Xls[o2][c + 1] = v.y; Xls[o2][c + 2] = v.z; Xls[o2][c + 3] = v.w;
  }
#pragma unroll
  for (int i = 0; i < 2; ++i) {
    const int gi = i * 1024 + t * 4;
    const int r = gi >> 7, c = gi & 127;
    const float4 v = *reinterpret_cast<const float4*>(&xrr[(size_t)r * F + f0 + c]);
    Rls[r][c] = v.x; Rls[r][c + 1] = v.y; Rls[r][c + 2] = v.z; Rls[r][c + 3] = v.w;
  }
  __syncthreads();

  const int ob = (t >> 4) << 2;
  const int fc = (t & 15) << 2;
  float acc[4][8];
#pragma unroll
  for (int i = 0; i < 4; ++i)
#pragma unroll
    for (int j = 0; j < 8; ++j) acc[i][j] = 0.f;

#pragma unroll 4
  for (int o2 = 0; o2 < O; ++o2) {
    const float4 xa = *reinterpret_cast<const float4*>(&Xls[o2][fc]);
    const float4 xb = *reinterpret_cast<const float4*>(&Xls[o2][fc + 64]);
#pragma unroll
    for (int io = 0; io < 4; ++io) {
      const float a = A1s[ob + io][o2];
      acc[io][0] += a * xa.x; acc[io][1] += a * xa.y; acc[io][2] += a * xa.z; acc[io][3] += a * xa.w;
      acc[io][4] += a * xb.x; acc[io][5] += a * xb.y; acc[io][6] += a * xb.z; acc[io][7] += a * xb.w;
    }
  }
#pragma unroll
  for (int r = 0; r < RN; ++r) {
    const float4 xa = *reinterpret_cast<const float4*>(&Rls[r][fc]);
    const float4 xb = *reinterpret_cast<const float4*>(&Rls[r][fc + 64]);
#pragma unroll
    for (int io = 0; io < 4; ++io) {
      const float a = A2s[ob + io][r];
      acc[io][0] += a * xa.x; acc[io][1] += a * xa.y; acc[io][2] += a * xa.z; acc[io][3] += a * xa.w;
      acc[io][4] += a * xb.x; acc[io][5] += a * xb.y; acc[io][6] += a * xb.z; acc[io][7] += a * xb.w;
    }
  }

#pragma unroll
  for (int io = 0; io < 4; ++io) {
    const size_t base = ((size_t)(b * O + ob + io)) * F + f0;
#pragma unroll
    for (int seg = 0; seg < 2; ++seg) {
      const size_t idx = base + seg * 64 + fc;
      const float4 s = *reinterpret_cast<const float4*>(&xs[idx]);
      const float4 bv = *reinterpret_cast<const float4*>(&bias[f0 + seg * 64 + fc]);
      const float4 xi = *reinterpret_cast<const float4*>(&xin[idx]);
      float4 o;
      o.x = tanhf(acc[io][seg * 4 + 0] + s.x + bv.x + xi.x);
      o.y = tanhf(acc[io][seg * 4 + 1] + s.y + bv.y + xi.y);
      o.z = tanhf(acc[io][seg * 4 + 2] + s.z + bv.z + xi.z);
      o.w = tanhf(acc[io][seg * 4 + 3] + s.w + bv.w + xi.w);
      *reinterpret_cast<float4*>(&xout[idx]) = o;
      if (XhO) {
        unsigned short h0, h1, h2, h3, l0, l1, l2, l3;
        split2(o.x, h0, l0); split2(o.y, h1, l1); split2(o.z, h2, l2); split2(o.w, h3, l3);
        uint2 hp, lp;
        hp.x = (unsigned)h0 | ((unsigned)h1 << 16); hp.y = (unsigned)h2 | ((unsigned)h3 << 16);
        lp.x = (unsigned)l0 | ((unsigned)l1 << 16); lp.y = (unsigned)l2 | ((unsigned)l3 << 16);
        *reinterpret_cast<uint2*>(&XhO[idx]) = hp;
        *reinterpret_cast<uint2*>(&XlO[idx]) = lp;
      }
    }
  }
}

extern "C" void kernel_launch(void* const* d_in, const int* in_sizes, int n_in,
                              void* d_out, int out_size, void* d_ws, size_t ws_size,
                              hipStream_t stream) {
  const float* x0    = (const float*)d_in[0];
  const float* A     = (const float*)d_in[1];
  const float* R     = (const float*)d_in[2];
  const float* Wself = (const float*)d_in[3];
  const float* bself = (const float*)d_in[4];
  const float* Wrel  = (const float*)d_in[5];
  const float* brel  = (const float*)d_in[6];
  float* out = (float*)d_out;

  float* ws  = (float*)d_ws;
  float* A1  = ws;                               // 1 MB
  float* A2  = A1 + (size_t)M * O;               // 0.25 MB
  float* xrr = A2 + (size_t)M * RN;              // 2 layers x RN x F
  float* xs  = xrr + (size_t)2 * RN * F;         // 16 MB
  float* xrx = xs + (size_t)M * F;               // 16 MB
  float* P1  = xrx + (size_t)M * F;              // 16 MB
  float* P2  = P1 + (size_t)M * F;               // 16 MB
  unsigned short* Xh  = (unsigned short*)(P2 + (size_t)M * F);     // 8 MB
  unsigned short* Xl  = Xh + (size_t)M * F;                        // 8 MB
  unsigned short* Wht = Xl + (size_t)M * F;      // 2 layers x [2048][1024] = 8 MB
  unsigned short* Wlt = Wht + (size_t)2 * 2048 * 1024;             // 8 MB
  // total ws use ~97 MB

  k_prep<<<8192, 256, 0, stream>>>(A, x0, A1, A2, Xh, Xl);
  k_prepW<<<4096 + 128, 256, 0, stream>>>(Wself, Wrel, brel, R, Wht, Wlt, xrr);

  // ---- layer 1 ----
  k_gemm_mfma<<<512, 512, 0, stream>>>(Xh, Xl, Wht, Wlt, xs, xrx, 1);
  k_agg<<<dim3(B, F / 128), 256, 0, stream>>>(A1, A2, xrx, P1, P2,
                                              xrr, xs, bself, x0, out,
                                              Xh, Xl, 0);
  // ---- layer 2 ----
  k_gemm_l2<<<1024, 512, 0, stream>>>(Xh, Xl,
                                      Wht + (size_t)2048 * 1024,
                                      Wlt + (size_t)2048 * 1024,
                                      xs, xrx, P1, P2);
  k_agg<<<dim3(B, F / 128), 256, 0, stream>>>(A1, A2, xrx, P1, P2,
                                              xrr + (size_t)RN * F, xs,
                                              bself + (size_t)F, out, out,
                                              nullptr, nullptr, 1);
}

// Round 16
// 166.079 us; speedup vs baseline: 1.4976x; 1.0230x over previous
//
#include <hip/hip_runtime.h>
#include <hip/hip_bf16.h>
#include <math.h>

#define B 64
#define O 64
#define F 1024
#define RN 16
#define RD 256
#define DEPTH 2
#define M (B*O)

typedef __attribute__((ext_vector_type(8))) _Float16 half8;
typedef __attribute__((ext_vector_type(4))) float f32x4;

#define RES_SCALE 2048.0f          // 2^11
#define RES_INV  (1.0f/2048.0f)

// ---------- fp16 split helpers: x = h + l*2^-11 (l stored pre-scaled) ----------
__device__ __forceinline__ unsigned short h2u(_Float16 h) {
  union { _Float16 h; unsigned short u; } c; c.h = h; return c.u;
}
__device__ __forceinline__ void split2(float x, unsigned short& h, unsigned short& l) {
  _Float16 hh = (_Float16)x;                       // RNE
  _Float16 ll = (_Float16)((x - (float)hh) * RES_SCALE);
  h = h2u(hh); l = h2u(ll);
}

__device__ __forceinline__ void gload_lds16(const unsigned short* g, void* l) {
  __builtin_amdgcn_global_load_lds(
      (const __attribute__((address_space(1))) unsigned int*)g,
      (__attribute__((address_space(3))) unsigned int*)l, 16, 0, 0);
}

// ------- merged prep 1: bid<4096 -> A reductions; else -> splitX --------------
__global__ __launch_bounds__(256) void k_prep(const float* __restrict__ A,
                                              const float* __restrict__ X,
                                              float* __restrict__ A1,
                                              float* __restrict__ A2,
                                              unsigned short* __restrict__ Xh,
                                              unsigned short* __restrict__ Xl) {
  __shared__ float row[O * RN];
  const int t = threadIdx.x;
  if (blockIdx.x < 4096) {
    const int bo = blockIdx.x;
    *reinterpret_cast<float4*>(&row[t * 4]) =
        *reinterpret_cast<const float4*>(&A[(size_t)bo * (O * RN) + t * 4]);
    __syncthreads();
    if (t < O) {
      float s = 0.f;
#pragma unroll
      for (int r = 0; r < RN; ++r) s += row[t * RN + r];
      A1[(size_t)bo * O + t] = s;
    } else if (t < O + RN) {
      const int r = t - O;
      float s = 0.f;
#pragma unroll
      for (int o2 = 0; o2 < O; ++o2) s += row[o2 * RN + r];
      A2[(size_t)bo * RN + r] = s;
    }
  } else {
    const size_t i = ((size_t)(blockIdx.x - 4096) * 256 + t) * 4;
    const float4 v = *reinterpret_cast<const float4*>(&X[i]);
    unsigned short h0, h1, h2, h3, l0, l1, l2, l3;
    split2(v.x, h0, l0); split2(v.y, h1, l1); split2(v.z, h2, l2); split2(v.w, h3, l3);
    uint2 hp, lp;
    hp.x = (unsigned)h0 | ((unsigned)h1 << 16); hp.y = (unsigned)h2 | ((unsigned)h3 << 16);
    lp.x = (unsigned)l0 | ((unsigned)l1 << 16); lp.y = (unsigned)l2 | ((unsigned)l3 << 16);
    *reinterpret_cast<uint2*>(&Xh[i]) = hp;
    *reinterpret_cast<uint2*>(&Xl[i]) = lp;
  }
}

// ------- merged prep 2: bid<4096 -> splitW both layers; else -> xrr -----------
__global__ __launch_bounds__(256) void k_prepW(const float* __restrict__ Wself,
                                               const float* __restrict__ Wrel,
                                               const float* __restrict__ brel,
                                               const float* __restrict__ R,
                                               unsigned short* __restrict__ Wht,
                                               unsigned short* __restrict__ Wlt,
                                               float* __restrict__ xrr) {
  __shared__ float T[32][33];
  const int t = threadIdx.x;
  const int bid = blockIdx.x;
  if (bid < 4096) {
    const int z = bid >> 10;                 // layer*2 + sel
    const int rem = bid & 1023;
    const int k0 = (rem & 31) * 32, n0 = (rem >> 5) * 32;
    const int layer = z >> 1;
    const int sel = z & 1;
    const float* W = sel ? (Wrel + (size_t)layer * (F + RD) * F)
                         : (Wself + (size_t)layer * F * F);
    const size_t obase = (size_t)layer * 2048 * 1024 + (size_t)(sel ? 1024 : 0) * 1024;
    const int r = t >> 3, c4 = (t & 7) << 2;
    const float4 v = *reinterpret_cast<const float4*>(&W[(size_t)(k0 + r) * 1024 + n0 + c4]);
    T[r][c4] = v.x; T[r][c4 + 1] = v.y; T[r][c4 + 2] = v.z; T[r][c4 + 3] = v.w;
    __syncthreads();
    unsigned short h[4], l[4];
#pragma unroll
    for (int j = 0; j < 4; ++j) split2(T[c4 + j][r], h[j], l[j]);
    uint2 hp, lp;
    hp.x = (unsigned)h[0] | ((unsigned)h[1] << 16); hp.y = (unsigned)h[2] | ((unsigned)h[3] << 16);
    lp.x = (unsigned)l[0] | ((unsigned)l[1] << 16); lp.y = (unsigned)l[2] | ((unsigned)l[3] << 16);
    const size_t o = obase + (size_t)(n0 + r) * 1024 + k0 + c4;
    *reinterpret_cast<uint2*>(&Wht[o]) = hp;
    *reinterpret_cast<uint2*>(&Wlt[o]) = lp;
  } else {
    const int r4 = bid - 4096;               // 0..127
    const int layer = r4 >> 6;
    const int idx = r4 & 63;
    const float* Wr = Wrel + (size_t)layer * (F + RD) * F + (size_t)F * F;
    const float* br = brel + (size_t)layer * F;
    const int r = idx >> 2;
    const int n = ((idx & 3) << 8) + t;
    float s = br[n];
    for (int k = 0; k < RD; ++k) s += R[r * RD + k] * Wr[(size_t)k * F + n];
    xrr[(size_t)layer * RN * F + (size_t)r * F + n] = s;
  }
}

// ---------------- staging + compute helpers (8-wave block, BK=64) ------------
// R11-proven: 32 chunks of 1KB (8 rows x 128B); wave w stages 4 chunks.
__device__ __forceinline__ void stage_tiles8(const unsigned short* __restrict__ Asrc,
                                             const unsigned short* __restrict__ Bsrc,
                                             int bm, int bn, int k0,
                                             int w, int lane,
                                             char* Al, char* Bl) {
  const int srow = lane >> 3;
  const int sin = (lane & 7) << 4;
#pragma unroll
  for (int i = 0; i < 4; ++i) {
    const int c = (w << 2) + i;          // 0..31, wave-uniform
    const int cc = c & 15;
    const int row = (cc << 3) + srow;
    const int inrow = sin ^ ((row & 7) << 4);   // pre-swizzled SOURCE byte
    const unsigned short* src = (c < 16) ? Asrc : Bsrc;
    const int rbase = (c < 16) ? bm : bn;
    char* ldst = (c < 16) ? Al : Bl;
    gload_lds16(src + ((size_t)(rbase + row) << 10) + k0 + (inrow >> 1), ldst + (cc << 10));
  }
}

// per-wave 64x32 output: 4 m-frags x 2 n-frags
__device__ __forceinline__ void compute_tile8(const char* Al, const char* Bl,
                                              int ar, int br, int kbyte,
                                              f32x4 (&acc)[4][2]) {
#pragma unroll
  for (int kk = 0; kk < 2; ++kk) {
    half8 a[4], b[2];
#pragma unroll
    for (int m = 0; m < 4; ++m) {
      const int row = ar + m * 16;
      const int off = (row << 7) + (((kk << 6) + kbyte) ^ ((row & 7) << 4));
      a[m] = *reinterpret_cast<const half8*>(&Al[off]);
    }
#pragma unroll
    for (int n = 0; n < 2; ++n) {
      const int row = br + n * 16;
      const int off = (row << 7) + (((kk << 6) + kbyte) ^ ((row & 7) << 4));
      b[n] = *reinterpret_cast<const half8*>(&Bl[off]);
    }
#pragma unroll
    for (int m = 0; m < 4; ++m)
#pragma unroll
      for (int n = 0; n < 2; ++n)
        acc[m][n] = __builtin_amdgcn_mfma_f32_16x16x32_f16(a[m], b[n], acc[m][n], 0, 0, 0);
  }
}

// 16-kt inner loop (K=1024), DOUBLE-BUFFERED single-barrier 2-phase:
// prologue stage(0->buf0); loop { stage(kt+1 -> buf^1); compute(buf); sync; }.
// Next tile's global_load_lds fly during compute; the barrier's automatic
// vmcnt(0) drain is then mostly complete. Buffer parity static via full unroll.
__device__ __forceinline__ void gemm_piece8(const unsigned short* __restrict__ Asrc,
                                            const unsigned short* __restrict__ Bsrc,
                                            int bm, int bn, int w, int lane,
                                            int ar, int br, int kbyte,
                                            char* Al0, char* Bl0,
                                            char* Al1, char* Bl1,
                                            f32x4 (&acc)[4][2]) {
  stage_tiles8(Asrc, Bsrc, bm, bn, 0, w, lane, Al0, Bl0);
  __syncthreads();
#pragma unroll
  for (int kt = 0; kt < 16; ++kt) {
    char* Ac = (kt & 1) ? Al1 : Al0;
    char* Bc = (kt & 1) ? Bl1 : Bl0;
    char* An = (kt & 1) ? Al0 : Al1;
    char* Bn = (kt & 1) ? Bl0 : Bl1;
    if (kt + 1 < 16)
      stage_tiles8(Asrc, Bsrc, bm, bn, (kt + 1) << 6, w, lane, An, Bn);
    compute_tile8(Ac, Bc, ar, br, kbyte, acc);
    __syncthreads();
  }
}

// ------- layer-1 fused MFMA GEMM ----------------------------------------------
// xrx half (bn>=1024): C = Xh@Wh + 2^-11*(Xh@Wl_st + Xl_st@Wh), K=3072.
// xs  half (bn< 1024): same (xs_full=1 for layer 1).
__global__ __launch_bounds__(512) void k_gemm_mfma(
    const unsigned short* __restrict__ Xh, const unsigned short* __restrict__ Xl,
    const unsigned short* __restrict__ Wht, const unsigned short* __restrict__ Wlt,
    float* __restrict__ xs, float* __restrict__ xrx, int xs_full) {
  __shared__ __align__(16) char Al0[128 * 128];
  __shared__ __align__(16) char Bl0[128 * 128];
  __shared__ __align__(16) char Al1[128 * 128];
  __shared__ __align__(16) char Bl1[128 * 128];
  const int t = threadIdx.x;
  const int lane = t & 63, w = t >> 6;
  const int bid = blockIdx.x;
  const int half = bid & 1;                 // 0 -> xrx (long), 1 -> xs
  int e = bid >> 1;
  e = (e & 7) * 32 + (e >> 3);               // XCD swizzle, bijective on 256
  const int bm = (e & 31) * 128;
  const int bn = (e >> 5) * 128 + (half ? 0 : 1024);
  const int wr = w >> 2, wc = w & 3;
  const bool full = (half == 0) || xs_full;

  f32x4 accM[4][2], accR[4][2];
#pragma unroll
  for (int m = 0; m < 4; ++m)
#pragma unroll
    for (int n = 0; n < 2; ++n) { accM[m][n] = (f32x4)0.f; accR[m][n] = (f32x4)0.f; }

  const int ar = wr * 64 + (lane & 15);
  const int br = wc * 32 + (lane & 15);
  const int kbyte = (lane >> 4) << 4;

  gemm_piece8(Xh, Wht, bm, bn, w, lane, ar, br, kbyte, Al0, Bl0, Al1, Bl1, accM);
  if (full) {
    gemm_piece8(Xh, Wlt, bm, bn, w, lane, ar, br, kbyte, Al0, Bl0, Al1, Bl1, accR);
    gemm_piece8(Xl, Wht, bm, bn, w, lane, ar, br, kbyte, Al0, Bl0, Al1, Bl1, accR);
  }

  float* dst = (bn < 1024) ? xs : xrx;
  const int coff = bn & 1023;
  const int lrow = (lane >> 4) << 2;
  const int lcol = lane & 15;
#pragma unroll
  for (int m = 0; m < 4; ++m)
#pragma unroll
    for (int n = 0; n < 2; ++n) {
      const int gr = bm + wr * 64 + m * 16 + lrow;
      const int gc = coff + wc * 32 + n * 16 + lcol;
#pragma unroll
      for (int i = 0; i < 4; ++i)
        dst[((size_t)(gr + i) << 10) + gc] = accM[m][n][i] + accR[m][n][i] * RES_INV;
    }
}

// ------- layer-2 GEMM: uniform 16-step blocks, 4 roles per tile-index ---------
// role 0: xs  = Xh@Wh (cols 0..1023)       role 1: xrx = Xh@Wh (cols 1024..)
// role 2: P1  = Xh@Wl_st (raw)             role 3: P2  = Xl_st@Wh (raw)
// consumer: xrx_eff = xrx + (P1+P2)*2^-11; xs needs no residual (last layer).
__global__ __launch_bounds__(512) void k_gemm_l2(
    const unsigned short* __restrict__ Xh, const unsigned short* __restrict__ Xl,
    const unsigned short* __restrict__ Wht, const unsigned short* __restrict__ Wlt,
    float* __restrict__ xs, float* __restrict__ xrx,
    float* __restrict__ P1, float* __restrict__ P2) {
  __shared__ __align__(16) char Al0[128 * 128];
  __shared__ __align__(16) char Bl0[128 * 128];
  __shared__ __align__(16) char Al1[128 * 128];
  __shared__ __align__(16) char Bl1[128 * 128];
  const int t = threadIdx.x;
  const int lane = t & 63, w = t >> 6;
  const int bid = blockIdx.x;
  const int role = bid & 3;
  int e = bid >> 2;
  e = (e & 7) * 32 + (e >> 3);               // XCD swizzle, bijective on 256
  const int bm = (e & 31) * 128;
  const int colblk = (e >> 5) * 128;
  const int bn = (role == 0) ? colblk : 1024 + colblk;
  const unsigned short* Asrc = (role == 3) ? Xl : Xh;
  const unsigned short* Bsrc = (role == 2) ? Wlt : Wht;
  float* dst = (role == 0) ? xs : (role == 1) ? xrx : (role == 2) ? P1 : P2;
  const int wr = w >> 2, wc = w & 3;

  f32x4 acc[4][2];
#pragma unroll
  for (int m = 0; m < 4; ++m)
#pragma unroll
    for (int n = 0; n < 2; ++n) acc[m][n] = (f32x4)0.f;

  const int ar = wr * 64 + (lane & 15);
  const int br = wc * 32 + (lane & 15);
  const int kbyte = (lane >> 4) << 4;

  gemm_piece8(Asrc, Bsrc, bm, bn, w, lane, ar, br, kbyte, Al0, Bl0, Al1, Bl1, acc);

  const int lrow = (lane >> 4) << 2;
  const int lcol = lane & 15;
#pragma unroll
  for (int m = 0; m < 4; ++m)
#pragma unroll
    for (int n = 0; n < 2; ++n) {
      const int gr = bm + wr * 64 + m * 16 + lrow;
      const int gc = colblk + wc * 32 + n * 16 + lcol;
#pragma unroll
      for (int i = 0; i < 4; ++i)
        dst[((size_t)(gr + i) << 10) + gc] = acc[m][n][i];
    }
}

// ------- out = tanh(xs + bself + A1[b]@xr_x[b] + A2[b]@xr_r + x_in) ----------
// use_p: xr_x = xrx + (P1+P2)*2^-11 (layer 2); else xr_x = xrx (layer 1).
__global__ __launch_bounds__(256) void k_agg(const float* __restrict__ A1,
                                             const float* __restrict__ A2,
                                             const float* __restrict__ xrx,
                                             const float* __restrict__ P1,
                                             const float* __restrict__ P2,
                                             const float* __restrict__ xrr,
                                             const float* __restrict__ xs,
                                             const float* __restrict__ bias,
                                             const float* __restrict__ xin,
                                             float* __restrict__ xout,
                                             unsigned short* __restrict__ XhO,
                                             unsigned short* __restrict__ XlO,
                                             int use_p) {
  __shared__ float A1s[O][O + 1];
  __shared__ float A2s[O][RN + 1];
  __shared__ float Xls[O][132];
  __shared__ float Rls[RN][132];
  const int b = blockIdx.x;
  const int f0 = blockIdx.y * 128;
  const int t = threadIdx.x;

#pragma unroll
  for (int i = 0; i < 4; ++i) {
    const int gi = i * 1024 + t * 4;
    const float4 v = *reinterpret_cast<const float4*>(&A1[(size_t)b * O * O + gi]);
    const int o = gi >> 6, c = gi & 63;
    A1s[o][c] = v.x; A1s[o][c + 1] = v.y; A1s[o][c + 2] = v.z; A1s[o][c + 3] = v.w;
  }
  {
    const int gi = t * 4;
    const float4 v = *reinterpret_cast<const float4*>(&A2[(size_t)b * O * RN + gi]);
    const int o = gi >> 4, c = gi & 15;
    A2s[o][c] = v.x; A2s[o][c + 1] = v.y; A2s[o][c + 2] = v.z; A2s[o][c + 3] = v.w;
  }
#pragma unroll
  for (int i = 0; i < 8; ++i) {
    const int gi = i * 1024 + t * 4;
    const int o2 = gi >> 7, c = gi & 127;
    const size_t pidx = ((size_t)(b * O + o2)) * F + f0 + c;
    float4 v = *reinterpret_cast<const float4*>(&xrx[pidx]);
    if (use_p) {
      const float4 p1 = *reinterpret_cast<const float4*>(&P1[pidx]);
      const float4 p2 = *reinterpret_cast<const float4*>(&P2[pidx]);
      v.x += (p1.x + p2.x) * RES_INV; v.y += (p1.y + p2.y) * RES_INV;
      v.z += (p1.z + p2.z) * RES_INV; v.w += (p1.w + p2.w) * RES_INV;
    }
    Xls[o2][c] = v.x; Xls[o2][c + 1] = v.y; Xls[o2][c + 2] = v.z; Xls[o2][c + 3] = v.w;
  }
#pragma unroll
  for (int i = 0; i < 2; ++i) {
    const int gi = i * 1024 + t * 4;
    const int r = gi >> 7, c = gi & 127;
    const float4 v = *reinterpret_cast<const float4*>(&xrr[(size_t)r * F + f0 + c]);
    Rls[r][c] = v.x; Rls[r][c + 1] = v.y; Rls[r][c + 2] = v.z; Rls[r][c + 3] = v.w;
  }
  __syncthreads();

  const int ob = (t >> 4) << 2;
  const int fc = (t & 15) << 2;
  float acc[4][8];
#pragma unroll
  for (int i = 0; i < 4; ++i)
#pragma unroll
    for (int j = 0; j < 8; ++j) acc[i][j] = 0.f;

#pragma unroll 4
  for (int o2 = 0; o2 < O; ++o2) {
    const float4 xa = *reinterpret_cast<const float4*>(&Xls[o2][fc]);
    const float4 xb = *reinterpret_cast<const float4*>(&Xls[o2][fc + 64]);
#pragma unroll
    for (int io = 0; io < 4; ++io) {
      const float a = A1s[ob + io][o2];
      acc[io][0] += a * xa.x; acc[io][1] += a * xa.y; acc[io][2] += a * xa.z; acc[io][3] += a * xa.w;
      acc[io][4] += a * xb.x; acc[io][5] += a * xb.y; acc[io][6] += a * xb.z; acc[io][7] += a * xb.w;
    }
  }
#pragma unroll
  for (int r = 0; r < RN; ++r) {
    const float4 xa = *reinterpret_cast<const float4*>(&Rls[r][fc]);
    const float4 xb = *reinterpret_cast<const float4*>(&Rls[r][fc + 64]);
#pragma unroll
    for (int io = 0; io < 4; ++io) {
      const float a = A2s[ob + io][r];
      acc[io][0] += a * xa.x; acc[io][1] += a * xa.y; acc[io][2] += a * xa.z; acc[io][3] += a * xa.w;
      acc[io][4] += a * xb.x; acc[io][5] += a * xb.y; acc[io][6] += a * xb.z; acc[io][7] += a * xb.w;
    }
  }

#pragma unroll
  for (int io = 0; io < 4; ++io) {
    const size_t base = ((size_t)(b * O + ob + io)) * F + f0;
#pragma unroll
    for (int seg = 0; seg < 2; ++seg) {
      const size_t idx = base + seg * 64 + fc;
      const float4 s = *reinterpret_cast<const float4*>(&xs[idx]);
      const float4 bv = *reinterpret_cast<const float4*>(&bias[f0 + seg * 64 + fc]);
      const float4 xi = *reinterpret_cast<const float4*>(&xin[idx]);
      float4 o;
      o.x = tanhf(acc[io][seg * 4 + 0] + s.x + bv.x + xi.x);
      o.y = tanhf(acc[io][seg * 4 + 1] + s.y + bv.y + xi.y);
      o.z = tanhf(acc[io][seg * 4 + 2] + s.z + bv.z + xi.z);
      o.w = tanhf(acc[io][seg * 4 + 3] + s.w + bv.w + xi.w);
      *reinterpret_cast<float4*>(&xout[idx]) = o;
      if (XhO) {
        unsigned short h0, h1, h2, h3, l0, l1, l2, l3;
        split2(o.x, h0, l0); split2(o.y, h1, l1); split2(o.z, h2, l2); split2(o.w, h3, l3);
        uint2 hp, lp;
        hp.x = (unsigned)h0 | ((unsigned)h1 << 16); hp.y = (unsigned)h2 | ((unsigned)h3 << 16);
        lp.x = (unsigned)l0 | ((unsigned)l1 << 16); lp.y = (unsigned)l2 | ((unsigned)l3 << 16);
        *reinterpret_cast<uint2*>(&XhO[idx]) = hp;
        *reinterpret_cast<uint2*>(&XlO[idx]) = lp;
      }
    }
  }
}

extern "C" void kernel_launch(void* const* d_in, const int* in_sizes, int n_in,
                              void* d_out, int out_size, void* d_ws, size_t ws_size,
                              hipStream_t stream) {
  const float* x0    = (const float*)d_in[0];
  const float* A     = (const float*)d_in[1];
  const float* R     = (const float*)d_in[2];
  const float* Wself = (const float*)d_in[3];
  const float* bself = (const float*)d_in[4];
  const float* Wrel  = (const float*)d_in[5];
  const float* brel  = (const float*)d_in[6];
  float* out = (float*)d_out;

  float* ws  = (float*)d_ws;
  float* A1  = ws;                               // 1 MB
  float* A2  = A1 + (size_t)M * O;               // 0.25 MB
  float* xrr = A2 + (size_t)M * RN;              // 2 layers x RN x F
  float* xs  = xrr + (size_t)2 * RN * F;         // 16 MB
  float* xrx = xs + (size_t)M * F;               // 16 MB
  float* P1  = xrx + (size_t)M * F;              // 16 MB
  float* P2  = P1 + (size_t)M * F;               // 16 MB
  unsigned short* Xh  = (unsigned short*)(P2 + (size_t)M * F);     // 8 MB
  unsigned short* Xl  = Xh + (size_t)M * F;                        // 8 MB
  unsigned short* Wht = Xl + (size_t)M * F;      // 2 layers x [2048][1024] = 8 MB
  unsigned short* Wlt = Wht + (size_t)2 * 2048 * 1024;             // 8 MB
  // total ws use ~97 MB

  k_prep<<<8192, 256, 0, stream>>>(A, x0, A1, A2, Xh, Xl);
  k_prepW<<<4096 + 128, 256, 0, stream>>>(Wself, Wrel, brel, R, Wht, Wlt, xrr);

  // ---- layer 1 ----
  k_gemm_mfma<<<512, 512, 0, stream>>>(Xh, Xl, Wht, Wlt, xs, xrx, 1);
  k_agg<<<dim3(B, F / 128), 256, 0, stream>>>(A1, A2, xrx, P1, P2,
                                              xrr, xs, bself, x0, out,
                                              Xh, Xl, 0);
  // ---- layer 2 ----
  k_gemm_l2<<<1024, 512, 0, stream>>>(Xh, Xl,
                                      Wht + (size_t)2048 * 1024,
                                      Wlt + (size_t)2048 * 1024,
                                      xs, xrx, P1, P2);
  k_agg<<<dim3(B, F / 128), 256, 0, stream>>>(A1, A2, xrx, P1, P2,
                                              xrr + (size_t)RN * F, xs,
                                              bself + (size_t)F, out, out,
                                              nullptr, nullptr, 1);
}